// Round 1
// baseline (47.957 us; speedup 1.0000x reference)
//
#include <hip/hip_runtime.h>

#define NB  4
#define C   19
#define HH  512
#define WW  1024
#define HW  (HH * WW)            // 524288
#define P4N (HW / 4)             // 131072 pixel-groups per n

// Pass 1: per-pixel softmax^2-sum + argmax, reduced per (n, class).
__global__ __launch_bounds__(256) void msql_pass1(
    const float* __restrict__ pred,
    float* __restrict__ g_ssum,          // [NB*C]
    unsigned* __restrict__ g_cnt)        // [NB*C]
{
    __shared__ float    s_ssum[C];
    __shared__ unsigned s_cnt[C];
    const int tid = threadIdx.x;
    if (tid < C) { s_ssum[tid] = 0.0f; s_cnt[tid] = 0u; }
    __syncthreads();

    const unsigned gid = blockIdx.x * 256u + (unsigned)tid;
    const unsigned n   = gid >> 17;              // / P4N (131072)
    const unsigned p4  = gid & (P4N - 1u);
    const float* base = pred + (size_t)n * C * HW + (size_t)p4 * 4;

    // 19 x float4: one coalesced 16B load per channel, register-resident.
    float4 x[C];
#pragma unroll
    for (int c = 0; c < C; ++c)
        x[c] = *reinterpret_cast<const float4*>(base + (size_t)c * HW);

#pragma unroll
    for (int j = 0; j < 4; ++j) {
        float m  = reinterpret_cast<const float*>(&x[0])[j];
        int  arg = 0;
#pragma unroll
        for (int c = 1; c < C; ++c) {
            float v = reinterpret_cast<const float*>(&x[c])[j];
            if (v > m) { m = v; arg = c; }       // strict > : first max, like jnp.argmax
        }
        float s1 = 0.0f, s2 = 0.0f;
#pragma unroll
        for (int c = 0; c < C; ++c) {
            float e = __expf(reinterpret_cast<const float*>(&x[c])[j] - m);
            s1 += e;
            s2 = fmaf(e, e, s2);                 // sum prob^2 numerator: e^2
        }
        const float S = s2 / (s1 * s1);          // sum_c softmax_c^2
        atomicAdd(&s_ssum[arg], S);
        atomicAdd(&s_cnt[arg], 1u);
    }

    __syncthreads();
    if (tid < C) {
        atomicAdd(&g_ssum[n * C + tid], s_ssum[tid]);
        atomicAdd(&g_cnt[n * C + tid], s_cnt[tid]);
    }
}

// Pass 2: class weights + final scalar loss.
__global__ __launch_bounds__(128) void msql_pass2(
    const float* __restrict__ g_ssum,
    const unsigned* __restrict__ g_cnt,
    float* __restrict__ out)
{
    const int t = threadIdx.x;
    float v = 0.0f;
    if (t < NB * C) {
        float h     = (float)g_cnt[t];
        float denom = powf(h, 0.2f) * powf((float)HW, 0.8f);
        denom       = fmaxf(denom, 1.0f);
        v = g_ssum[t] / denom;                   // class_w * per-class S-sum
    }
#pragma unroll
    for (int off = 32; off > 0; off >>= 1)
        v += __shfl_down(v, off, 64);
    __shared__ float ws[2];
    if ((t & 63) == 0) ws[t >> 6] = v;
    __syncthreads();
    if (t == 0)
        out[0] = -(ws[0] + ws[1]) / (float)(NB * C);
}

extern "C" void kernel_launch(void* const* d_in, const int* in_sizes, int n_in,
                              void* d_out, int out_size, void* d_ws, size_t ws_size,
                              hipStream_t stream) {
    const float* pred = (const float*)d_in[0];
    float*    out    = (float*)d_out;
    float*    g_ssum = (float*)d_ws;
    unsigned* g_cnt  = (unsigned*)((char*)d_ws + NB * C * sizeof(float));

    // d_ws is poisoned once and never re-poisoned: zero our 608 bytes every call.
    hipMemsetAsync(d_ws, 0, NB * C * (sizeof(float) + sizeof(unsigned)), stream);

    const int total_groups = NB * HW / 4;        // 524288 threads, exact cover
    msql_pass1<<<dim3(total_groups / 256), dim3(256), 0, stream>>>(pred, g_ssum, g_cnt);
    msql_pass2<<<dim3(1), dim3(128), 0, stream>>>(g_ssum, g_cnt, out);
}

// Round 2
// 37.435 us; speedup vs baseline: 1.2811x; 1.2811x over previous
//
#include <hip/hip_runtime.h>

#define NB  4
#define C   19
#define HW  (512 * 1024)           // 524288 pixels per n
#define BLOCKS_PER_N 1024          // each block: 256 threads x 2 pixels = 512 px
#define NBLK (NB * BLOCKS_PER_N)   // 4096 blocks
#define NBIN (NB * C)              // 76

// Pass 1: per-pixel softmax^2-sum + argmax, per-block partials (no global atomics).
__global__ __launch_bounds__(256) void msql_pass1(
    const float* __restrict__ pred,
    float2* __restrict__ part)     // [NBIN][1024] of (ssum, count)
{
    __shared__ float    s_ssum[C];
    __shared__ unsigned s_cnt[C];
    const int tid = threadIdx.x;
    if (tid < C) { s_ssum[tid] = 0.0f; s_cnt[tid] = 0u; }
    __syncthreads();

    const unsigned b  = blockIdx.x;
    const unsigned n  = b >> 10;                       // block / 1024
    const unsigned p2 = ((b & 1023u) << 8) + (unsigned)tid;   // pixel-pair idx in n
    const float* base = pred + (size_t)n * ((size_t)C * HW) + (size_t)p2 * 2;

    // 19 x float2: coalesced 8B/lane per channel, register-resident (38 VGPRs).
    float2 x[C];
#pragma unroll
    for (int c = 0; c < C; ++c)
        x[c] = *reinterpret_cast<const float2*>(base + (size_t)c * HW);

#pragma unroll
    for (int j = 0; j < 2; ++j) {
        float m  = j ? x[0].y : x[0].x;
        int  arg = 0;
#pragma unroll
        for (int c = 1; c < C; ++c) {
            float v = j ? x[c].y : x[c].x;
            if (v > m) { m = v; arg = c; }             // strict >: first max (jnp.argmax)
        }
        float s1 = 0.0f, s2 = 0.0f;
#pragma unroll
        for (int c = 0; c < C; ++c) {
            float e = __expf((j ? x[c].y : x[c].x) - m);
            s1 += e;
            s2 = fmaf(e, e, s2);
        }
        const float S = s2 / (s1 * s1);                // sum_c softmax_c^2
        atomicAdd(&s_ssum[arg], S);
        atomicAdd(&s_cnt[arg], 1u);
    }

    __syncthreads();
    if (tid < C) {
        // bin = c*NB + n ; 1024 contiguous slots per bin; every slot written.
        part[(((unsigned)tid * NB + n) << 10) + (b & 1023u)] =
            make_float2(s_ssum[tid], (float)s_cnt[tid]);   // counts <= 512: exact in fp32
    }
}

// Pass 2: reduce each bin's 1024 partials, apply class weight.
__global__ __launch_bounds__(256) void msql_pass2(
    const float2* __restrict__ part,
    float* __restrict__ vout)      // [NBIN]
{
    const int bin = blockIdx.x;
    const int t   = threadIdx.x;
    float ss = 0.0f, cc = 0.0f;
#pragma unroll
    for (int i = 0; i < 4; ++i) {
        float2 p = part[((size_t)bin << 10) + t + (i << 8)];
        ss += p.x; cc += p.y;
    }
#pragma unroll
    for (int off = 32; off > 0; off >>= 1) {
        ss += __shfl_down(ss, off, 64);
        cc += __shfl_down(cc, off, 64);
    }
    __shared__ float l_ss[4], l_cc[4];
    if ((t & 63) == 0) { l_ss[t >> 6] = ss; l_cc[t >> 6] = cc; }
    __syncthreads();
    if (t == 0) {
        float S = (l_ss[0] + l_ss[1]) + (l_ss[2] + l_ss[3]);
        float h = (l_cc[0] + l_cc[1]) + (l_cc[2] + l_cc[3]);
        float denom = fmaxf(powf(h, 0.2f) * powf((float)HW, 0.8f), 1.0f);
        vout[bin] = S / denom;
    }
}

// Pass 3: combine 76 bin values -> scalar loss (deterministic, no atomics).
__global__ __launch_bounds__(128) void msql_pass3(
    const float* __restrict__ vout,
    float* __restrict__ out)
{
    const int t = threadIdx.x;
    float v = (t < NBIN) ? vout[t] : 0.0f;
#pragma unroll
    for (int off = 32; off > 0; off >>= 1)
        v += __shfl_down(v, off, 64);
    __shared__ float ws[2];
    if ((t & 63) == 0) ws[t >> 6] = v;
    __syncthreads();
    if (t == 0)
        out[0] = -(ws[0] + ws[1]) / (float)NBIN;
}

extern "C" void kernel_launch(void* const* d_in, const int* in_sizes, int n_in,
                              void* d_out, int out_size, void* d_ws, size_t ws_size,
                              hipStream_t stream) {
    const float* pred = (const float*)d_in[0];
    float* out  = (float*)d_out;
    float2* part = (float2*)d_ws;                               // NBIN*1024*8 B = 623 KB
    float*  vout = (float*)((char*)d_ws + (size_t)NBIN * 1024 * sizeof(float2));

    msql_pass1<<<dim3(NBLK), dim3(256), 0, stream>>>(pred, part);
    msql_pass2<<<dim3(NBIN), dim3(256), 0, stream>>>(part, vout);
    msql_pass3<<<dim3(1), dim3(128), 0, stream>>>(vout, out);
}